// Round 9
// baseline (29.678 us; speedup 1.0000x reference)
//
#include <hip/hip_runtime.h>

constexpr int BLK = 256;
constexpr int P   = 2;     // adjacent points per thread (one packed pair)

typedef float v2f __attribute__((ext_vector_type(2)));

__device__ __forceinline__ v2f splat(float s) { return (v2f){s, s}; }
__device__ __forceinline__ v2f pk_fma(v2f a, v2f b, v2f c) {
    return __builtin_elementwise_fma(a, b, c);
}
__device__ __forceinline__ v2f pk_max0(v2f a) {
    return __builtin_elementwise_max(a, (v2f){0.0f, 0.0f});
}
__device__ __forceinline__ v2f pk_min0(v2f a) {
    return __builtin_elementwise_min(a, (v2f){0.0f, 0.0f});
}
__device__ __forceinline__ v2f pk_clamp(v2f a, float lo, float hi) {
    return __builtin_elementwise_min(__builtin_elementwise_max(a, splat(lo)), splat(hi));
}

// ---------- native transcendentals ----------
__device__ __forceinline__ float fast_rcp(float x) { return __builtin_amdgcn_rcpf(x); }

__device__ __forceinline__ float fast_exp2(float x) {
#if __has_builtin(__builtin_amdgcn_exp2f)
    return __builtin_amdgcn_exp2f(x);
#else
    return __expf(x * 0.6931471805599453f);
#endif
}

#define LOG2E 1.4426950408889634f

__device__ __forceinline__ v2f pk_exp2(v2f t) { return (v2f){fast_exp2(t.x), fast_exp2(t.y)}; }
// one hardware rcp for both components: rcp(d.x), rcp(d.y) via rcp(d.x*d.y)
__device__ __forceinline__ v2f pk_rcp_paired(v2f d) {
    float r = fast_rcp(d.x * d.y);
    return (v2f){r * d.y, r * d.x};
}

// ---------- activations on a packed pair ----------
template<int A> __device__ __forceinline__ v2f act2(v2f z);
// 0: relu
template<> __device__ __forceinline__ v2f act2<0>(v2f z) { return pk_max0(z); }
// 1: tanh — depth-7 continued-fraction Pade, clamp +-4.5, single paired rcp.
template<> __device__ __forceinline__ v2f act2<1>(v2f z) {
    v2f xc = pk_clamp(z, -4.5f, 4.5f);
    v2f u  = xc * xc;
    v2f n  = pk_fma(pk_fma(u + 378.0f, u, splat(17325.0f)), u, splat(135135.0f)) * xc;
    v2f d  = pk_fma(pk_fma(pk_fma(u, splat(28.0f), splat(3150.0f)), u, splat(62370.0f)),
                    u, splat(135135.0f));
    return n * pk_rcp_paired(d);
}
// 2: elu = max(z,0) + min(e^z - 1, 0)   (branch-free, inf-safe)
template<> __device__ __forceinline__ v2f act2<2>(v2f z) {
    v2f em = pk_exp2(z * LOG2E) - 1.0f;
    return pk_max0(z) + pk_min0(em);
}
// 3: silu = z * sigmoid(z); clamp arg so paired rcp can't overflow/denormal
template<> __device__ __forceinline__ v2f act2<3>(v2f z) {
    v2f zc = pk_clamp(z, -30.0f, 30.0f);
    v2f d  = pk_exp2(zc * (-LOG2E)) + 1.0f;
    return z * pk_rcp_paired(d);
}
// 4: gelu ~= z * sigmoid(1.702 z); clamp likewise
template<> __device__ __forceinline__ v2f act2<4>(v2f z) {
    v2f zc = pk_clamp(z, -18.0f, 18.0f);
    v2f d  = pk_exp2(zc * (-1.702f * LOG2E)) + 1.0f;
    return z * pk_rcp_paired(d);
}
// 5: none
template<> __device__ __forceinline__ v2f act2<5>(v2f z) { return z; }
// 6: selu = sc*max(z,0) + min(sc*al*(e^z-1), 0)
template<> __device__ __forceinline__ v2f act2<6>(v2f z) {
    const float sc   = 1.0507009873554805f;
    const float scal = 1.7580993408473766f;   // sc*alpha
    v2f e = pk_exp2(z * LOG2E);
    v2f n = pk_fma(splat(scal), e, splat(-scal));
    return pk_fma(pk_max0(z), splat(sc), pk_min0(n));
}
// 7: softplus = max(z,0) + ln(1+2^{-log2e*|z|}) via deg-4 poly-ln on (1,2]
template<> __device__ __forceinline__ v2f act2<7>(v2f z) {
    v2f a = __builtin_elementwise_abs(z) * (-LOG2E);
    v2f m = pk_exp2(a) + 1.0f;                 // in (1, 2]
    v2f p = pk_fma(splat(-0.056570851f), m, splat(0.44717955f));
    p = pk_fma(p, m, splat(-1.4699568f));
    p = pk_fma(p, m, splat(2.8212026f));
    p = pk_fma(p, m, splat(-1.7417939f));      // ~= ln(m), |err| < 5e-4
    return pk_max0(z) + p;
}

// ---------- one expert, compile-time index A -> all weight reads uniform (s_load) ----------
template<int A>
__device__ __forceinline__ void run_expert(const float* __restrict__ W1,
                                           const float* __restrict__ b1,
                                           const float* __restrict__ W2,
                                           const float* __restrict__ ew,
                                           v2f re, v2f im, v2f am, v2f& acc) {
    v2f accE = (v2f){0.0f, 0.0f};
#pragma unroll
    for (int h = 0; h < 16; ++h) {
        const float wre = W1[A * 48 + h];        // W1: (8,3,16)
        const float wim = W1[A * 48 + 16 + h];
        const float wam = W1[A * 48 + 32 + h];
        const float bb  = b1[A * 16 + h];
        const float w2  = W2[A * 16 + h];
        v2f z = pk_fma(re, splat(wre),
                pk_fma(im, splat(wim),
                pk_fma(am, splat(wam), splat(bb))));
        accE = pk_fma(act2<A>(z), splat(w2), accE);
    }
    acc = pk_fma(accE, splat(ew[A]), acc);
}

__device__ __forceinline__ void atomic_addf(float* p, float v) {
    __hip_atomic_fetch_add(p, v, __ATOMIC_RELAXED, __HIP_MEMORY_SCOPE_AGENT);
}

// Expert-split: even blocks do {relu,tanh,elu,silu}+analytic, odd blocks do
// {gelu,none,selu,softplus}. Doubles resident waves (8/SIMD) at constant
// total issue; halves per-wave straight-line code. Out combined via fp32
// atomics (exactly 2 commutative adds per element -> deterministic).
__global__ __launch_bounds__(BLK, 8)
void moe_kernel(const float* __restrict__ x,
                const float* __restrict__ W1,
                const float* __restrict__ b1,
                const float* __restrict__ W2,
                const float* __restrict__ b2,
                const float* __restrict__ ew,
                float* __restrict__ out, int npts) {
    const int group = blockIdx.x & 1;
    const int pr = (blockIdx.x >> 1) * BLK + threadIdx.x;   // pair index
    if (pr * P >= npts) return;

    // two adjacent points: one float4 load (16B/lane, coalesced)
    float4 v = reinterpret_cast<const float4*>(x)[pr];
    v2f re = (v2f){v.x, v.z};
    v2f im = (v2f){v.y, v.w};
    v2f r2 = pk_fma(re, re, im * im);
    v2f am = (v2f){__builtin_amdgcn_sqrtf(r2.x), __builtin_amdgcn_sqrtf(r2.y)};

    v2f acc = (v2f){0.0f, 0.0f};

    if (group == 0) {
        // analytic experts + folded b2 bias; raw v_sin/v_cos (arg in revolutions)
        float bconst = 0.0f;
#pragma unroll
        for (int i = 0; i < 8; ++i) bconst = fmaf(ew[i], b2[i], bconst);
        const float INV2PI = 0.15915494309189535f;
        v2f s = am * INV2PI;
        v2f sn = (v2f){__builtin_amdgcn_sinf(s.x), __builtin_amdgcn_sinf(s.y)};
        v2f cs = (v2f){__builtin_amdgcn_cosf(s.x), __builtin_amdgcn_cosf(s.y)};

        acc = pk_fma(splat(ew[8]),
                     __builtin_elementwise_abs(re) + __builtin_elementwise_abs(im),
                     splat(bconst));                              // 'abs'
        acc = pk_fma(splat(ew[9]), am, acc);                      // 'modulus'
        acc = pk_fma(splat(ew[10]), sn, acc);                     // 'sin'
        acc = pk_fma(splat(ew[11]), cs, acc);                     // 'cos'

        run_expert<0>(W1, b1, W2, ew, re, im, am, acc);  // relu
        run_expert<1>(W1, b1, W2, ew, re, im, am, acc);  // tanh (Pade)
        run_expert<2>(W1, b1, W2, ew, re, im, am, acc);  // elu
        run_expert<3>(W1, b1, W2, ew, re, im, am, acc);  // silu (paired rcp)
    } else {
        run_expert<4>(W1, b1, W2, ew, re, im, am, acc);  // gelu (paired rcp)
        run_expert<5>(W1, b1, W2, ew, re, im, am, acc);  // none
        run_expert<6>(W1, b1, W2, ew, re, im, am, acc);  // selu
        run_expert<7>(W1, b1, W2, ew, re, im, am, acc);  // softplus (poly-ln)
    }

    float* o = out + pr * P;
    atomic_addf(&o[0], acc.x);
    atomic_addf(&o[1], acc.y);
}

extern "C" void kernel_launch(void* const* d_in, const int* in_sizes, int n_in,
                              void* d_out, int out_size, void* d_ws, size_t ws_size,
                              hipStream_t stream) {
    const float* x  = (const float*)d_in[0];
    const float* W1 = (const float*)d_in[1];
    const float* b1 = (const float*)d_in[2];
    const float* W2 = (const float*)d_in[3];
    const float* b2 = (const float*)d_in[4];
    const float* ew = (const float*)d_in[5];
    float* out = (float*)d_out;

    const int npts = in_sizes[0] / 2;  // (B,S,C,2) -> B*S*C points
    const int pair_blocks = (npts + BLK * P - 1) / (BLK * P);

    hipMemsetAsync(out, 0, (size_t)out_size * sizeof(float), stream);
    hipLaunchKernelGGL(moe_kernel, dim3(2 * pair_blocks), dim3(BLK), 0, stream,
                       x, W1, b1, W2, b2, ew, out, npts);
}

// Round 10
// 24.435 us; speedup vs baseline: 1.2145x; 1.2145x over previous
//
#include <hip/hip_runtime.h>

constexpr int BLK = 256;   // P = 1 point per thread -> 2048 blocks, 8 waves/SIMD

// ---------- native transcendentals ----------
__device__ __forceinline__ float fast_rcp(float x) { return __builtin_amdgcn_rcpf(x); }

__device__ __forceinline__ float fast_exp2(float x) {
#if __has_builtin(__builtin_amdgcn_exp2f)
    return __builtin_amdgcn_exp2f(x);
#else
    return __expf(x * 0.6931471805599453f);
#endif
}

#define LOG2E 1.4426950408889634f

__device__ __forceinline__ float max0(float x) { return fmaxf(x, 0.0f); }
__device__ __forceinline__ float min0(float x) { return fminf(x, 0.0f); }

// ---------- scalar activations ----------
template<int A> __device__ __forceinline__ float act_fn(float z);
// 0: relu
template<> __device__ __forceinline__ float act_fn<0>(float z) { return max0(z); }
// 1: tanh = 1 - 2*rcp(1+e^{2z})   (inf-safe)
template<> __device__ __forceinline__ float act_fn<1>(float z) {
    float e = fast_exp2(z * (2.0f * LOG2E));
    return fmaf(-2.0f, fast_rcp(e + 1.0f), 1.0f);
}
// 2: elu = max(z,0) + min(e^z - 1, 0)   (branch-free)
template<> __device__ __forceinline__ float act_fn<2>(float z) {
    float em = fast_exp2(z * LOG2E) - 1.0f;
    return max0(z) + min0(em);
}
// 3: silu = z * sigmoid(z)
template<> __device__ __forceinline__ float act_fn<3>(float z) {
    float d = fast_exp2(z * (-LOG2E)) + 1.0f;
    return z * fast_rcp(d);
}
// 4: gelu ~= z * sigmoid(1.702 z)
template<> __device__ __forceinline__ float act_fn<4>(float z) {
    float d = fast_exp2(z * (-1.702f * LOG2E)) + 1.0f;
    return z * fast_rcp(d);
}
// 5: none
template<> __device__ __forceinline__ float act_fn<5>(float z) { return z; }
// 6: selu = sc*max(z,0) + min(sc*al*(e^z-1), 0)
template<> __device__ __forceinline__ float act_fn<6>(float z) {
    const float sc   = 1.0507009873554805f;
    const float scal = 1.7580993408473766f;   // sc*alpha
    float e = fast_exp2(z * LOG2E);
    float n = fmaf(scal, e, -scal);
    return fmaf(max0(z), sc, min0(n));
}
// 7: softplus = max(z,0) + ln(m), m = 1+e^{-|z|} in (1,2], deg-4 poly-ln
template<> __device__ __forceinline__ float act_fn<7>(float z) {
    float m = fast_exp2(fabsf(z) * (-LOG2E)) + 1.0f;
    float p = fmaf(-0.056570851f, m, 0.44717955f);
    p = fmaf(p, m, -1.4699568f);
    p = fmaf(p, m, 2.8212026f);
    p = fmaf(p, m, -1.7417939f);               // ~= ln(m), |err| < 5e-4
    return max0(z) + p;
}

// ---------- one expert, compile-time index A -> all weight reads uniform (s_load) ----------
template<int A>
__device__ __forceinline__ void run_expert(const float* __restrict__ W1,
                                           const float* __restrict__ b1,
                                           const float* __restrict__ W2,
                                           const float* __restrict__ ew,
                                           float re, float im, float am, float& acc) {
    float accE = 0.0f;
#pragma unroll
    for (int h = 0; h < 16; ++h) {
        const float wre = W1[A * 48 + h];        // W1: (8,3,16)
        const float wim = W1[A * 48 + 16 + h];
        const float wam = W1[A * 48 + 32 + h];
        const float bb  = b1[A * 16 + h];
        const float w2  = W2[A * 16 + h];
        float z = fmaf(re, wre, fmaf(im, wim, fmaf(am, wam, bb)));
        accE = fmaf(act_fn<A>(z), w2, accE);
    }
    acc = fmaf(accE, ew[A], acc);
    __builtin_amdgcn_sched_barrier(0);   // bound the scheduling window per expert
}

__global__ __launch_bounds__(BLK, 8)   // 8 waves/SIMD target: VGPR cap 64
void moe_kernel(const float* __restrict__ x,
                const float* __restrict__ W1,
                const float* __restrict__ b1,
                const float* __restrict__ W2,
                const float* __restrict__ b2,
                const float* __restrict__ ew,
                float* __restrict__ out, int npts) {
    const int p = blockIdx.x * BLK + threadIdx.x;
    if (p >= npts) return;

    float bconst = 0.0f;
#pragma unroll
    for (int i = 0; i < 8; ++i) bconst = fmaf(ew[i], b2[i], bconst);

    // one point per thread: float2 load (8B/lane, coalesced)
    float2 v = reinterpret_cast<const float2*>(x)[p];
    const float re = v.x, im = v.y;
    const float am = __builtin_amdgcn_sqrtf(fmaf(re, re, im * im));

    // analytic experts + folded b2 bias; raw v_sin/v_cos (arg in revolutions)
    const float INV2PI = 0.15915494309189535f;
    const float s  = am * INV2PI;
    const float sn = __builtin_amdgcn_sinf(s);
    const float cs = __builtin_amdgcn_cosf(s);

    float acc = fmaf(ew[8], fabsf(re) + fabsf(im), bconst);  // 'abs' + folded b2
    acc = fmaf(ew[9],  am, acc);                             // 'modulus'
    acc = fmaf(ew[10], sn, acc);                             // 'sin'
    acc = fmaf(ew[11], cs, acc);                             // 'cos'

    run_expert<0>(W1, b1, W2, ew, re, im, am, acc);  // relu
    run_expert<1>(W1, b1, W2, ew, re, im, am, acc);  // tanh
    run_expert<2>(W1, b1, W2, ew, re, im, am, acc);  // elu
    run_expert<3>(W1, b1, W2, ew, re, im, am, acc);  // silu
    run_expert<4>(W1, b1, W2, ew, re, im, am, acc);  // gelu
    run_expert<5>(W1, b1, W2, ew, re, im, am, acc);  // none
    run_expert<6>(W1, b1, W2, ew, re, im, am, acc);  // selu
    run_expert<7>(W1, b1, W2, ew, re, im, am, acc);  // softplus

    out[p] = acc;
}

extern "C" void kernel_launch(void* const* d_in, const int* in_sizes, int n_in,
                              void* d_out, int out_size, void* d_ws, size_t ws_size,
                              hipStream_t stream) {
    const float* x  = (const float*)d_in[0];
    const float* W1 = (const float*)d_in[1];
    const float* b1 = (const float*)d_in[2];
    const float* W2 = (const float*)d_in[3];
    const float* b2 = (const float*)d_in[4];
    const float* ew = (const float*)d_in[5];
    float* out = (float*)d_out;

    const int npts = in_sizes[0] / 2;  // (B,S,C,2) -> B*S*C points
    const int blocks = (npts + BLK - 1) / BLK;
    hipLaunchKernelGGL(moe_kernel, dim3(blocks), dim3(BLK), 0, stream,
                       x, W1, b1, W2, b2, ew, out, npts);
}

// Round 11
// 20.290 us; speedup vs baseline: 1.4627x; 1.2043x over previous
//
#include <hip/hip_runtime.h>

constexpr int BLK   = 256;   // 128 pair-slots x 2 expert-groups
constexpr int SLOTS = 128;

typedef float v2f __attribute__((ext_vector_type(2)));

__device__ __forceinline__ v2f splat(float s) { return (v2f){s, s}; }
__device__ __forceinline__ v2f pk_fma(v2f a, v2f b, v2f c) {
    return __builtin_elementwise_fma(a, b, c);
}
__device__ __forceinline__ v2f pk_max0(v2f a) {
    return __builtin_elementwise_max(a, (v2f){0.0f, 0.0f});
}
__device__ __forceinline__ v2f pk_min0(v2f a) {
    return __builtin_elementwise_min(a, (v2f){0.0f, 0.0f});
}

// ---------- native transcendentals ----------
__device__ __forceinline__ float fast_rcp(float x) { return __builtin_amdgcn_rcpf(x); }

__device__ __forceinline__ float fast_exp2(float x) {
#if __has_builtin(__builtin_amdgcn_exp2f)
    return __builtin_amdgcn_exp2f(x);
#else
    return __expf(x * 0.6931471805599453f);
#endif
}
__device__ __forceinline__ float fast_log2(float x) {
#if __has_builtin(__builtin_amdgcn_logf)
    return __builtin_amdgcn_logf(x);
#else
    return __log2f(x);
#endif
}

#define LOG2E 1.4426950408889634f
#define LN2   0.6931471805599453f

__device__ __forceinline__ v2f pk_exp2(v2f t) { return (v2f){fast_exp2(t.x), fast_exp2(t.y)}; }
__device__ __forceinline__ v2f pk_rcp(v2f t)  { return (v2f){fast_rcp(t.x),  fast_rcp(t.y)};  }

// ---------- activations (EXACT round-6 forms — best measured) ----------
template<int A> __device__ __forceinline__ v2f act2(v2f z);
// 0: relu
template<> __device__ __forceinline__ v2f act2<0>(v2f z) { return pk_max0(z); }
// 1: tanh = 1 - 2*rcp(1+e^{2z})
template<> __device__ __forceinline__ v2f act2<1>(v2f z) {
    v2f e = pk_exp2(z * (2.0f * LOG2E));
    v2f r = pk_rcp(e + 1.0f);
    return pk_fma(splat(-2.0f), r, splat(1.0f));
}
// 2: elu = max(z,0) + min(e^z - 1, 0)
template<> __device__ __forceinline__ v2f act2<2>(v2f z) {
    v2f em = pk_exp2(z * LOG2E) - 1.0f;
    return pk_max0(z) + pk_min0(em);
}
// 3: silu = z * rcp(1+e^{-z})
template<> __device__ __forceinline__ v2f act2<3>(v2f z) {
    v2f e = pk_exp2(z * (-LOG2E));
    return z * pk_rcp(e + 1.0f);
}
// 4: gelu ~= z * sigmoid(1.702 z)
template<> __device__ __forceinline__ v2f act2<4>(v2f z) {
    v2f e = pk_exp2(z * (-1.702f * LOG2E));
    return z * pk_rcp(e + 1.0f);
}
// 5: none
template<> __device__ __forceinline__ v2f act2<5>(v2f z) { return z; }
// 6: selu
template<> __device__ __forceinline__ v2f act2<6>(v2f z) {
    const float sc   = 1.0507009873554805f;
    const float scal = 1.7580993408473766f;   // sc*alpha
    v2f e = pk_exp2(z * LOG2E);
    v2f n = pk_fma(splat(scal), e, splat(-scal));
    return pk_fma(pk_max0(z), splat(sc), pk_min0(n));
}
// 7: softplus = max(z,0) + ln2*log2(1+e^{-|z|})
template<> __device__ __forceinline__ v2f act2<7>(v2f z) {
    v2f a = __builtin_elementwise_abs(z) * (-LOG2E);
    v2f d = pk_exp2(a) + 1.0f;
    v2f l = (v2f){fast_log2(d.x), fast_log2(d.y)};
    return pk_fma(splat(LN2), l, pk_max0(z));
}

// ---------- one expert, compile-time index A -> all weight reads uniform (s_load) ----------
template<int A>
__device__ __forceinline__ void run_expert(const float* __restrict__ W1,
                                           const float* __restrict__ b1,
                                           const float* __restrict__ W2,
                                           const float* __restrict__ ew,
                                           v2f re, v2f im, v2f am, v2f& acc) {
    v2f accE = (v2f){0.0f, 0.0f};
#pragma unroll
    for (int h = 0; h < 16; ++h) {
        const float wre = W1[A * 48 + h];        // W1: (8,3,16)
        const float wim = W1[A * 48 + 16 + h];
        const float wam = W1[A * 48 + 32 + h];
        const float bb  = b1[A * 16 + h];
        const float w2  = W2[A * 16 + h];
        v2f z = pk_fma(re, splat(wre),
                pk_fma(im, splat(wim),
                pk_fma(am, splat(wam), splat(bb))));
        accE = pk_fma(act2<A>(z), splat(w2), accE);
    }
    acc = pk_fma(accE, splat(ew[A]), acc);
    __builtin_amdgcn_sched_barrier(0);   // bound the scheduling window per expert
}

// In-block expert split: threads [0,128) = group 0 ({relu,tanh,elu,silu} +
// analytic), threads [128,256) = group 1 ({gelu,none,selu,softplus}), both
// over the SAME 128 point-pairs. Combine via LDS (1 barrier, no atomics).
// Doubles resident waves (8/SIMD) at ~constant total issue.
__global__ __launch_bounds__(BLK, 8)
void moe_kernel(const float* __restrict__ x,
                const float* __restrict__ W1,
                const float* __restrict__ b1,
                const float* __restrict__ W2,
                const float* __restrict__ b2,
                const float* __restrict__ ew,
                float* __restrict__ out, int npts) {
    __shared__ v2f s_part[SLOTS];

    const int slot = threadIdx.x & (SLOTS - 1);
    const int grp  = threadIdx.x >> 7;            // wave-uniform (waves 0-1 vs 2-3)
    const int pr   = blockIdx.x * SLOTS + slot;   // pair index
    const bool ok  = (pr * 2 < npts);

    float4 v = ok ? reinterpret_cast<const float4*>(x)[pr]
                  : make_float4(0.0f, 0.0f, 0.0f, 0.0f);
    v2f re = (v2f){v.x, v.z};
    v2f im = (v2f){v.y, v.w};
    v2f r2 = pk_fma(re, re, im * im);
    v2f am = (v2f){__builtin_amdgcn_sqrtf(r2.x), __builtin_amdgcn_sqrtf(r2.y)};

    v2f acc = (v2f){0.0f, 0.0f};

    if (grp == 1) {
        run_expert<4>(W1, b1, W2, ew, re, im, am, acc);  // gelu
        run_expert<5>(W1, b1, W2, ew, re, im, am, acc);  // none
        run_expert<6>(W1, b1, W2, ew, re, im, am, acc);  // selu
        run_expert<7>(W1, b1, W2, ew, re, im, am, acc);  // softplus
        s_part[slot] = acc;
    } else {
        float bconst = 0.0f;
#pragma unroll
        for (int i = 0; i < 8; ++i) bconst = fmaf(ew[i], b2[i], bconst);

        v2f sn = (v2f){__sinf(am.x), __sinf(am.y)};
        v2f cs = (v2f){__cosf(am.x), __cosf(am.y)};

        acc = pk_fma(splat(ew[8]),
                     __builtin_elementwise_abs(re) + __builtin_elementwise_abs(im),
                     splat(bconst));                              // 'abs' + folded b2
        acc = pk_fma(splat(ew[9]), am, acc);                      // 'modulus'
        acc = pk_fma(splat(ew[10]), sn, acc);                     // 'sin'
        acc = pk_fma(splat(ew[11]), cs, acc);                     // 'cos'

        run_expert<0>(W1, b1, W2, ew, re, im, am, acc);  // relu
        run_expert<1>(W1, b1, W2, ew, re, im, am, acc);  // tanh
        run_expert<2>(W1, b1, W2, ew, re, im, am, acc);  // elu
        run_expert<3>(W1, b1, W2, ew, re, im, am, acc);  // silu
    }

    __syncthreads();

    if (grp == 0 && ok) {
        v2f tot = acc + s_part[slot];
        reinterpret_cast<float2*>(out)[pr] = make_float2(tot.x, tot.y);
    }
}

extern "C" void kernel_launch(void* const* d_in, const int* in_sizes, int n_in,
                              void* d_out, int out_size, void* d_ws, size_t ws_size,
                              hipStream_t stream) {
    const float* x  = (const float*)d_in[0];
    const float* W1 = (const float*)d_in[1];
    const float* b1 = (const float*)d_in[2];
    const float* W2 = (const float*)d_in[3];
    const float* b2 = (const float*)d_in[4];
    const float* ew = (const float*)d_in[5];
    float* out = (float*)d_out;

    const int npts  = in_sizes[0] / 2;           // (B,S,C,2) -> B*S*C points
    const int pairs = (npts + 1) / 2;
    const int blocks = (pairs + SLOTS - 1) / SLOTS;
    hipLaunchKernelGGL(moe_kernel, dim3(blocks), dim3(BLK), 0, stream,
                       x, W1, b1, W2, b2, ew, out, npts);
}